// Round 1
// baseline (1113.184 us; speedup 1.0000x reference)
//
#include <hip/hip_runtime.h>
#include <stdint.h>

// ---------------------------------------------------------------------------
// CustomLSTMCell: B=8192, CIN=512, H=2048
//   xp = x @ Wp^T + bp                        [B,H]
//   comb = tanh(LN_{4096}(concat(xp,h)))      [B,2H]
//   gates g in {f,i,c2,o}: LN_H(comb @ Wg^T + bg) -> sigmoid/tanh
//   cell = LN_H(f*c + i*cc); hid = tanh(LN_H(o*tanh(cell)))
//   out = [hid; cell]  (f32, [2,B,H])
// Strategy: bf16 MFMA GEMMs (m97 structure), fused LN kernels.
// ---------------------------------------------------------------------------

#define BM 128
#define BN 128
#define BK 32

typedef __attribute__((ext_vector_type(8))) short short8;
typedef __attribute__((ext_vector_type(4))) float f32x4;

__device__ __forceinline__ unsigned short f2bf(float x) {
  union { float f; uint32_t u; } v; v.f = x;
  uint32_t r = v.u + 0x7FFFu + ((v.u >> 16) & 1u);   // RNE
  return (unsigned short)(r >> 16);
}
__device__ __forceinline__ float bf2f(unsigned short u) {
  union { uint32_t u; float f; } v; v.u = ((uint32_t)u) << 16; return v.f;
}
__device__ __forceinline__ void unpack8(uint4 p, float* o) {
  uint32_t w[4] = {p.x, p.y, p.z, p.w};
#pragma unroll
  for (int k = 0; k < 4; k++) {
    o[2*k]   = bf2f((unsigned short)(w[k] & 0xffffu));
    o[2*k+1] = bf2f((unsigned short)(w[k] >> 16));
  }
}
__device__ __forceinline__ uint4 pack8(const float* s) {
  uint4 r;
  r.x = (uint32_t)f2bf(s[0]) | ((uint32_t)f2bf(s[1]) << 16);
  r.y = (uint32_t)f2bf(s[2]) | ((uint32_t)f2bf(s[3]) << 16);
  r.z = (uint32_t)f2bf(s[4]) | ((uint32_t)f2bf(s[5]) << 16);
  r.w = (uint32_t)f2bf(s[6]) | ((uint32_t)f2bf(s[7]) << 16);
  return r;
}
__device__ __forceinline__ float tanh_fast(float x) {
  x = fminf(fmaxf(x, -15.f), 15.f);
  float e = __expf(-2.f * x);
  return (1.f - e) / (1.f + e);
}
__device__ __forceinline__ float sigmoid_fast(float x) {
  return 1.f / (1.f + __expf(-x));
}

// f32 -> bf16 convert, 8 elems/thread
__global__ __launch_bounds__(256)
void cvt_f32_bf16(const float* __restrict__ src, unsigned short* __restrict__ dst, int n8) {
  int i = blockIdx.x * 256 + threadIdx.x;
  if (i >= n8) return;
  const float4* s4 = (const float4*)src;
  float4 a = s4[2*i], b = s4[2*i+1];
  float t[8] = {a.x,a.y,a.z,a.w,b.x,b.y,b.z,b.w};
  ((uint4*)dst)[i] = pack8(t);
}

// ---------------------------------------------------------------------------
// GEMM: C[m,n] = sum_k A[m,k]*Bw[n,k] + bias(n), A/Bw bf16 row-major, C bf16.
// m97 structure: 128x128 tile, BK=32, 4 waves each 64x64 (4x4 of 16x16x32 MFMA),
// global_load_lds width-16 staging, 2-barrier K-loop.
// N multiple of 128; gate bias selected by col>>11.
// ---------------------------------------------------------------------------
__global__ __launch_bounds__(256, 3)
void gemm_bt_bf16(const unsigned short* __restrict__ A,
                  const unsigned short* __restrict__ Bw,
                  const float* __restrict__ b0, const float* __restrict__ b1,
                  const float* __restrict__ b2, const float* __restrict__ b3,
                  unsigned short* __restrict__ C,
                  int M, int N, int K) {
  __shared__ unsigned short As[BM * BK];   // 8 KB
  __shared__ unsigned short Bs[BN * BK];   // 8 KB
  const int tid  = threadIdx.x;
  const int lane = tid & 63;
  const int wave = tid >> 6;
  const int wr = wave >> 1, wc = wave & 1;
  const int bm = blockIdx.y * BM;
  const int bn = blockIdx.x * BN;

  // staging: thread -> (row = chunk*64 + wave*16 + lane/4, col = (lane%4)*8)
  const int srow = wave * 16 + (lane >> 2);
  const int scol = (lane & 3) * 8;
  const unsigned short* gA0 = A  + (size_t)(bm + srow)      * K + scol;
  const unsigned short* gA1 = A  + (size_t)(bm + 64 + srow) * K + scol;
  const unsigned short* gB0 = Bw + (size_t)(bn + srow)      * K + scol;
  const unsigned short* gB1 = Bw + (size_t)(bn + 64 + srow) * K + scol;
  unsigned short* lA0 = As + (wave * 16) * BK;        // wave-uniform LDS base
  unsigned short* lA1 = As + (64 + wave * 16) * BK;
  unsigned short* lB0 = Bs + (wave * 16) * BK;
  unsigned short* lB1 = Bs + (64 + wave * 16) * BK;

  const int cl = lane & 15, q = lane >> 4;
  const int a_base = (wr * 64 + cl) * BK + q * 8;
  const int b_base = (wc * 64 + cl) * BK + q * 8;

  f32x4 acc[4][4];
#pragma unroll
  for (int i = 0; i < 4; i++)
#pragma unroll
    for (int j = 0; j < 4; j++) acc[i][j] = (f32x4){0.f, 0.f, 0.f, 0.f};

  for (int k0 = 0; k0 < K; k0 += BK) {
    __syncthreads();
    __builtin_amdgcn_global_load_lds(
        (const __attribute__((address_space(1))) void*)(gA0 + k0),
        (__attribute__((address_space(3))) void*)lA0, 16, 0, 0);
    __builtin_amdgcn_global_load_lds(
        (const __attribute__((address_space(1))) void*)(gA1 + k0),
        (__attribute__((address_space(3))) void*)lA1, 16, 0, 0);
    __builtin_amdgcn_global_load_lds(
        (const __attribute__((address_space(1))) void*)(gB0 + k0),
        (__attribute__((address_space(3))) void*)lB0, 16, 0, 0);
    __builtin_amdgcn_global_load_lds(
        (const __attribute__((address_space(1))) void*)(gB1 + k0),
        (__attribute__((address_space(3))) void*)lB1, 16, 0, 0);
    __syncthreads();

    short8 af[4], bv[4];
#pragma unroll
    for (int i = 0; i < 4; i++) af[i] = *(const short8*)(As + a_base + i * 16 * BK);
#pragma unroll
    for (int j = 0; j < 4; j++) bv[j] = *(const short8*)(Bs + b_base + j * 16 * BK);
#pragma unroll
    for (int i = 0; i < 4; i++)
#pragma unroll
      for (int j = 0; j < 4; j++)
        acc[i][j] = __builtin_amdgcn_mfma_f32_16x16x32_bf16(af[i], bv[j], acc[i][j], 0, 0, 0);
  }

  // epilogue: C/D layout col=lane&15 (n), row=(lane>>4)*4+reg (m)
#pragma unroll
  for (int i = 0; i < 4; i++) {
    int row0 = bm + wr * 64 + i * 16 + q * 4;
#pragma unroll
    for (int j = 0; j < 4; j++) {
      int col = bn + wc * 64 + j * 16 + cl;
      int gate = col >> 11;   // uniform per 16-wide tile (boundaries at 2048)
      const float* bp = (gate == 0) ? b0 : (gate == 1) ? b1 : (gate == 2) ? b2 : b3;
      float bvl = bp[col & 2047];
#pragma unroll
      for (int r = 0; r < 4; r++)
        C[(size_t)(row0 + r) * N + col] = f2bf(acc[i][j][r] + bvl);
    }
  }
}

__device__ __forceinline__ float2 block_sum2(float a, float b, float* scr, int t) {
#pragma unroll
  for (int o = 32; o; o >>= 1) { a += __shfl_xor(a, o); b += __shfl_xor(b, o); }
  __syncthreads();                       // protect scr from previous use
  if ((t & 63) == 0) { scr[(t >> 6) * 2] = a; scr[(t >> 6) * 2 + 1] = b; }
  __syncthreads();
  return make_float2(scr[0] + scr[2] + scr[4] + scr[6],
                     scr[1] + scr[3] + scr[5] + scr[7]);
}

// LN over concat(xp[b], h[b]) width 4096, then tanh, store bf16 combined row.
__global__ __launch_bounds__(256)
void ln_tanh_combined(const unsigned short* __restrict__ xp,
                      const float* __restrict__ h,
                      const float* __restrict__ g_ln, const float* __restrict__ b_ln,
                      unsigned short* __restrict__ comb) {
  __shared__ float red[8];
  const int b = blockIdx.x, t = threadIdx.x;
  float xv[8], hv[8];
  unpack8(((const uint4*)(xp + (size_t)b * 2048))[t], xv);
  const float4* hr = (const float4*)(h + (size_t)b * 2048);
  float4 h0 = hr[2*t], h1 = hr[2*t+1];
  hv[0]=h0.x; hv[1]=h0.y; hv[2]=h0.z; hv[3]=h0.w;
  hv[4]=h1.x; hv[5]=h1.y; hv[6]=h1.z; hv[7]=h1.w;
  float s = 0.f, ss = 0.f;
#pragma unroll
  for (int e = 0; e < 8; e++) {
    s += xv[e] + hv[e];
    ss += xv[e]*xv[e] + hv[e]*hv[e];
  }
  float2 r = block_sum2(s, ss, red, t);
  float mean = r.x * (1.f/4096.f);
  float var  = r.y * (1.f/4096.f) - mean*mean;
  float rs = rsqrtf(var + 1e-5f);
  float o0[8], o1[8];
  const int j0 = t * 8;
#pragma unroll
  for (int e = 0; e < 8; e++) {
    int j = j0 + e;
    o0[e] = tanh_fast((xv[e] - mean) * rs * g_ln[j] + b_ln[j]);
  }
#pragma unroll
  for (int e = 0; e < 8; e++) {
    int j = 2048 + j0 + e;
    o1[e] = tanh_fast((hv[e] - mean) * rs * g_ln[j] + b_ln[j]);
  }
  uint4* cr = (uint4*)(comb + (size_t)b * 4096);
  cr[t] = pack8(o0);
  cr[256 + t] = pack8(o1);
}

// Per batch row: 4 gate LNs + activations, cell LN, hidden LN, write f32 out.
__global__ __launch_bounds__(256)
void finalize(const unsigned short* __restrict__ gates, const float* __restrict__ c,
              const float* __restrict__ g_f,  const float* __restrict__ bt_f,
              const float* __restrict__ g_i,  const float* __restrict__ bt_i,
              const float* __restrict__ g_c2, const float* __restrict__ bt_c2,
              const float* __restrict__ g_o,  const float* __restrict__ bt_o,
              const float* __restrict__ g_cn, const float* __restrict__ b_cn,
              const float* __restrict__ g_hn, const float* __restrict__ b_hn,
              float* __restrict__ out) {
  __shared__ float red32[32];
  const int b = blockIdx.x, t = threadIdx.x;
  const unsigned short* gr = gates + (size_t)b * 8192;
  float fv[8], iv[8], c2v[8], ov[8];
  unpack8(((const uint4*)(gr        ))[t], fv);
  unpack8(((const uint4*)(gr + 2048))[t], iv);
  unpack8(((const uint4*)(gr + 4096))[t], c2v);
  unpack8(((const uint4*)(gr + 6144))[t], ov);

  // combined stats reduction for all 4 gates: s[f,i,c2,o] + ss[...]
  float s[8] = {0,0,0,0,0,0,0,0};
#pragma unroll
  for (int e = 0; e < 8; e++) {
    s[0] += fv[e];  s[1] += fv[e]*fv[e];
    s[2] += iv[e];  s[3] += iv[e]*iv[e];
    s[4] += c2v[e]; s[5] += c2v[e]*c2v[e];
    s[6] += ov[e];  s[7] += ov[e]*ov[e];
  }
#pragma unroll
  for (int o = 32; o; o >>= 1)
#pragma unroll
    for (int q2 = 0; q2 < 8; q2++) s[q2] += __shfl_xor(s[q2], o);
  if ((t & 63) == 0) {
#pragma unroll
    for (int q2 = 0; q2 < 8; q2++) red32[(t >> 6) * 8 + q2] = s[q2];
  }
  __syncthreads();
#pragma unroll
  for (int q2 = 0; q2 < 8; q2++)
    s[q2] = red32[q2] + red32[8 + q2] + red32[16 + q2] + red32[24 + q2];

  const float inv = 1.f / 2048.f;
  float m_f = s[0]*inv, rs_f = rsqrtf(s[1]*inv - m_f*m_f + 1e-5f);
  float m_i = s[2]*inv, rs_i = rsqrtf(s[3]*inv - m_i*m_i + 1e-5f);
  float m_c = s[4]*inv, rs_c = rsqrtf(s[5]*inv - m_c*m_c + 1e-5f);
  float m_o = s[6]*inv, rs_o = rsqrtf(s[7]*inv - m_o*m_o + 1e-5f);

  const int j0 = t * 8;
  float cv[8];
  const float4* crp = (const float4*)(c + (size_t)b * 2048);
  float4 c0 = crp[2*t], c1 = crp[2*t+1];
  cv[0]=c0.x; cv[1]=c0.y; cv[2]=c0.z; cv[3]=c0.w;
  cv[4]=c1.x; cv[5]=c1.y; cv[6]=c1.z; cv[7]=c1.w;

  float cellraw[8], os[8];
  float s2 = 0.f, ss2 = 0.f;
#pragma unroll
  for (int e = 0; e < 8; e++) {
    int j = j0 + e;
    float fgate = sigmoid_fast((fv[e]  - m_f) * rs_f * g_f[j]  + bt_f[j]);
    float igate = sigmoid_fast((iv[e]  - m_i) * rs_i * g_i[j]  + bt_i[j]);
    float cgate = tanh_fast   ((c2v[e] - m_c) * rs_c * g_c2[j] + bt_c2[j]);
    os[e]       = sigmoid_fast((ov[e]  - m_o) * rs_o * g_o[j]  + bt_o[j]);
    cellraw[e] = fgate * cv[e] + igate * cgate;
    s2 += cellraw[e]; ss2 += cellraw[e]*cellraw[e];
  }
  float2 rc = block_sum2(s2, ss2, red32, t);
  float m2 = rc.x * inv, rs2 = rsqrtf(rc.y * inv - m2*m2 + 1e-5f);

  float nc[8], hraw[8];
  float s3 = 0.f, ss3 = 0.f;
#pragma unroll
  for (int e = 0; e < 8; e++) {
    int j = j0 + e;
    nc[e] = (cellraw[e] - m2) * rs2 * g_cn[j] + b_cn[j];
    hraw[e] = os[e] * tanh_fast(nc[e]);
    s3 += hraw[e]; ss3 += hraw[e]*hraw[e];
  }
  float2 rh = block_sum2(s3, ss3, red32, t);
  float m3 = rh.x * inv, rs3 = rsqrtf(rh.y * inv - m3*m3 + 1e-5f);

  float nh[8];
#pragma unroll
  for (int e = 0; e < 8; e++) {
    int j = j0 + e;
    nh[e] = tanh_fast((hraw[e] - m3) * rs3 * g_hn[j] + b_hn[j]);
  }
  // out: [0][b][:] = next_hidden, [1][b][:] = next_cell ; B*H = 16777216
  float4* oh = (float4*)(out + (size_t)b * 2048 + j0);
  oh[0] = make_float4(nh[0], nh[1], nh[2], nh[3]);
  oh[1] = make_float4(nh[4], nh[5], nh[6], nh[7]);
  float4* oc = (float4*)(out + 16777216ull + (size_t)b * 2048 + j0);
  oc[0] = make_float4(nc[0], nc[1], nc[2], nc[3]);
  oc[1] = make_float4(nc[4], nc[5], nc[6], nc[7]);
}

extern "C" void kernel_launch(void* const* d_in, const int* in_sizes, int n_in,
                              void* d_out, int out_size, void* d_ws, size_t ws_size,
                              hipStream_t stream) {
  const float* x      = (const float*)d_in[0];
  const float* h      = (const float*)d_in[1];
  const float* c      = (const float*)d_in[2];
  const float* W_proj = (const float*)d_in[3];
  const float* b_proj = (const float*)d_in[4];
  const float* g_ln   = (const float*)d_in[5];
  const float* b_ln   = (const float*)d_in[6];
  const float* g_cn   = (const float*)d_in[7];
  const float* b_cn   = (const float*)d_in[8];
  const float* g_hn   = (const float*)d_in[9];
  const float* b_hn   = (const float*)d_in[10];
  const float* W_f    = (const float*)d_in[11];
  const float* b_f    = (const float*)d_in[12];
  const float* g_f    = (const float*)d_in[13];
  const float* bt_f   = (const float*)d_in[14];
  const float* W_i    = (const float*)d_in[15];
  const float* b_i    = (const float*)d_in[16];
  const float* g_i    = (const float*)d_in[17];
  const float* bt_i   = (const float*)d_in[18];
  const float* W_c2   = (const float*)d_in[19];
  const float* b_c2   = (const float*)d_in[20];
  const float* g_c2   = (const float*)d_in[21];
  const float* bt_c2  = (const float*)d_in[22];
  const float* W_o    = (const float*)d_in[23];
  const float* b_o    = (const float*)d_in[24];
  const float* g_o    = (const float*)d_in[25];
  const float* bt_o   = (const float*)d_in[26];
  float* out = (float*)d_out;
  char* ws = (char*)d_ws;

  // ws layout (256 MB total):
  //   [0,   64M): Wcat bf16 [8192][4096]  (W_f;W_i;W_c2;W_o)
  //   [64M, 128M): combined bf16 [8192][4096]
  //   [128M,256M): gates bf16 [8192][8192]   (phase 2)
  //     overlaid phase 1: x_bf16 (8M) | wp_bf16 (2M) | xp_bf16 (32M)
  unsigned short* Wcat  = (unsigned short*)(ws);
  unsigned short* comb  = (unsigned short*)(ws + 67108864ull);
  unsigned short* gates = (unsigned short*)(ws + 134217728ull);
  unsigned short* xbf   = (unsigned short*)(ws + 134217728ull);
  unsigned short* wpbf  = (unsigned short*)(ws + 142606336ull);
  unsigned short* xpbf  = (unsigned short*)(ws + 144703488ull);

  // 1) converts to bf16
  cvt_f32_bf16<<<2048, 256, 0, stream>>>(x, xbf, 524288);           // 8192*512
  cvt_f32_bf16<<<512,  256, 0, stream>>>(W_proj, wpbf, 131072);     // 2048*512
  cvt_f32_bf16<<<4096, 256, 0, stream>>>(W_f,  Wcat,             1048576);
  cvt_f32_bf16<<<4096, 256, 0, stream>>>(W_i,  Wcat +  8388608,  1048576);
  cvt_f32_bf16<<<4096, 256, 0, stream>>>(W_c2, Wcat + 16777216,  1048576);
  cvt_f32_bf16<<<4096, 256, 0, stream>>>(W_o,  Wcat + 25165824,  1048576);

  // 2) xp = x @ Wp^T + bp   (M=8192, N=2048, K=512) -> bf16
  dim3 g1(2048 / BN, 8192 / BM);
  gemm_bt_bf16<<<g1, 256, 0, stream>>>(xbf, wpbf, b_proj, b_proj, b_proj, b_proj,
                                       xpbf, 8192, 2048, 512);

  // 3) combined = tanh(LN(concat(xp,h)))
  ln_tanh_combined<<<8192, 256, 0, stream>>>(xpbf, h, g_ln, b_ln, comb);

  // 4) gates = comb @ Wcat^T + bias   (M=8192, N=8192, K=4096) -> bf16
  dim3 g2(8192 / BN, 8192 / BM);
  gemm_bt_bf16<<<g2, 256, 0, stream>>>(comb, Wcat, b_f, b_i, b_c2, b_o,
                                       gates, 8192, 8192, 4096);

  // 5) gate LNs + activations + cell/hidden LNs -> out
  finalize<<<8192, 256, 0, stream>>>(gates, c, g_f, bt_f, g_i, bt_i, g_c2, bt_c2,
                                     g_o, bt_o, g_cn, b_cn, g_hn, b_hn, out);
}

// Round 2
// 1099.461 us; speedup vs baseline: 1.0125x; 1.0125x over previous
//
#include <hip/hip_runtime.h>
#include <stdint.h>

// ---------------------------------------------------------------------------
// CustomLSTMCell: B=8192, CIN=512, H=2048
//   xp = x @ Wp^T + bp                        [B,H]
//   comb = tanh(LN_{4096}(concat(xp,h)))      [B,2H]
//   gates g in {f,i,c2,o}: LN_H(comb @ Wg^T + bg) -> sigmoid/tanh
//   cell = LN_H(f*c + i*cc); hid = tanh(LN_H(o*tanh(cell)))
//   out = [hid; cell]  (f32, [2,B,H])
// R2: XOR-swizzled LDS (kills 6.7e7 bank-conflict cycles), merged converts.
// ---------------------------------------------------------------------------

#define BM 128
#define BN 128
#define BK 32

typedef __attribute__((ext_vector_type(8))) short short8;
typedef __attribute__((ext_vector_type(4))) float f32x4;

__device__ __forceinline__ unsigned short f2bf(float x) {
  union { float f; uint32_t u; } v; v.f = x;
  uint32_t r = v.u + 0x7FFFu + ((v.u >> 16) & 1u);   // RNE
  return (unsigned short)(r >> 16);
}
__device__ __forceinline__ float bf2f(unsigned short u) {
  union { uint32_t u; float f; } v; v.u = ((uint32_t)u) << 16; return v.f;
}
__device__ __forceinline__ void unpack8(uint4 p, float* o) {
  uint32_t w[4] = {p.x, p.y, p.z, p.w};
#pragma unroll
  for (int k = 0; k < 4; k++) {
    o[2*k]   = bf2f((unsigned short)(w[k] & 0xffffu));
    o[2*k+1] = bf2f((unsigned short)(w[k] >> 16));
  }
}
__device__ __forceinline__ uint4 pack8(const float* s) {
  uint4 r;
  r.x = (uint32_t)f2bf(s[0]) | ((uint32_t)f2bf(s[1]) << 16);
  r.y = (uint32_t)f2bf(s[2]) | ((uint32_t)f2bf(s[3]) << 16);
  r.z = (uint32_t)f2bf(s[4]) | ((uint32_t)f2bf(s[5]) << 16);
  r.w = (uint32_t)f2bf(s[6]) | ((uint32_t)f2bf(s[7]) << 16);
  return r;
}
__device__ __forceinline__ float tanh_fast(float x) {
  x = fminf(fmaxf(x, -15.f), 15.f);
  float e = __expf(-2.f * x);
  return (1.f - e) / (1.f + e);
}
__device__ __forceinline__ float sigmoid_fast(float x) {
  return 1.f / (1.f + __expf(-x));
}

// ---------------------------------------------------------------------------
// Merged f32->bf16 convert for x, W_proj, and the 4 gate weights.
// Hardcoded segment sizes: x 8192*512, Wp 2048*512, each W 2048*4096.
// ---------------------------------------------------------------------------
__global__ __launch_bounds__(256)
void cvt_all(const float* __restrict__ x, const float* __restrict__ Wp,
             const float* __restrict__ Wf, const float* __restrict__ Wi,
             const float* __restrict__ Wc2, const float* __restrict__ Wo,
             unsigned short* __restrict__ xbf, unsigned short* __restrict__ wpbf,
             unsigned short* __restrict__ Wcat) {
  const int blk = blockIdx.x;
  const float* src;
  unsigned short* dst;
  int i;
  if (blk < 2048) {                // x: 524288 groups of 8
    src = x; dst = xbf; i = blk * 256 + threadIdx.x;
  } else if (blk < 2560) {         // W_proj: 131072 groups
    src = Wp; dst = wpbf; i = (blk - 2048) * 256 + threadIdx.x;
  } else {                         // four W's: 1048576 groups each
    int b2 = blk - 2560;
    int w = b2 >> 12;
    src = (w == 0) ? Wf : (w == 1) ? Wi : (w == 2) ? Wc2 : Wo;
    dst = Wcat + (size_t)w * 8388608;
    i = (b2 & 4095) * 256 + threadIdx.x;
  }
  const float4* s4 = (const float4*)src;
  float4 a = s4[2*i], b = s4[2*i+1];
  float t[8] = {a.x,a.y,a.z,a.w,b.x,b.y,b.z,b.w};
  ((uint4*)dst)[i] = pack8(t);
}

// ---------------------------------------------------------------------------
// GEMM: C[m,n] = sum_k A[m,k]*Bw[n,k] + bias(n), A/Bw bf16 row-major, C bf16.
// 128x128 tile, BK=32, 4 waves each 64x64 (4x4 of 16x16x32 MFMA),
// global_load_lds width-16 staging, XOR-swizzled LDS chunks:
//   LDS (row, chunk c) holds global (row, c ^ (row&3))  [chunk = 8 bf16 = 16B]
// Staging writes are contiguous lane*16B (global_load_lds constraint); the
// swizzle is applied by permuting each lane's *global* source column, and
// un-applied on the ds_read base. Spreads b128 reads evenly over 32 banks.
// ---------------------------------------------------------------------------
__global__ __launch_bounds__(256, 4)
void gemm_bt_bf16(const unsigned short* __restrict__ A,
                  const unsigned short* __restrict__ Bw,
                  const float* __restrict__ b0, const float* __restrict__ b1,
                  const float* __restrict__ b2, const float* __restrict__ b3,
                  unsigned short* __restrict__ C,
                  int M, int N, int K) {
  __shared__ unsigned short As[BM * BK];   // 8 KB
  __shared__ unsigned short Bs[BN * BK];   // 8 KB
  const int tid  = threadIdx.x;
  const int lane = tid & 63;
  const int wave = tid >> 6;
  const int wr = wave >> 1, wc = wave & 1;
  const int bm = blockIdx.y * BM;
  const int bn = blockIdx.x * BN;

  // staging: lane -> (row = wave*16 + lane/4, chunk = lane%4), source column
  // XOR-swizzled so LDS chunk c holds global chunk c^(row&3).
  const int srow = wave * 16 + (lane >> 2);
  const int schunk = (lane & 3) ^ ((lane >> 2) & 3);
  const int scol = schunk * 8;
  const unsigned short* gA0 = A  + (size_t)(bm + srow)      * K + scol;
  const unsigned short* gA1 = A  + (size_t)(bm + 64 + srow) * K + scol;
  const unsigned short* gB0 = Bw + (size_t)(bn + srow)      * K + scol;
  const unsigned short* gB1 = Bw + (size_t)(bn + 64 + srow) * K + scol;
  unsigned short* lA0 = As + (wave * 16) * BK;        // wave-uniform LDS base
  unsigned short* lA1 = As + (64 + wave * 16) * BK;
  unsigned short* lB0 = Bs + (wave * 16) * BK;
  unsigned short* lB1 = Bs + (64 + wave * 16) * BK;

  const int cl = lane & 15, q = lane >> 4;
  // fragment read: global chunk q of row r lives at LDS chunk q^(r&3);
  // r&3 == cl&3 for all i (rows step by 16).
  const int sq = q ^ (cl & 3);
  const int a_base = (wr * 64 + cl) * BK + sq * 8;
  const int b_base = (wc * 64 + cl) * BK + sq * 8;

  f32x4 acc[4][4];
#pragma unroll
  for (int i = 0; i < 4; i++)
#pragma unroll
    for (int j = 0; j < 4; j++) acc[i][j] = (f32x4){0.f, 0.f, 0.f, 0.f};

  for (int k0 = 0; k0 < K; k0 += BK) {
    __syncthreads();
    __builtin_amdgcn_global_load_lds(
        (const __attribute__((address_space(1))) void*)(gA0 + k0),
        (__attribute__((address_space(3))) void*)lA0, 16, 0, 0);
    __builtin_amdgcn_global_load_lds(
        (const __attribute__((address_space(1))) void*)(gA1 + k0),
        (__attribute__((address_space(3))) void*)lA1, 16, 0, 0);
    __builtin_amdgcn_global_load_lds(
        (const __attribute__((address_space(1))) void*)(gB0 + k0),
        (__attribute__((address_space(3))) void*)lB0, 16, 0, 0);
    __builtin_amdgcn_global_load_lds(
        (const __attribute__((address_space(1))) void*)(gB1 + k0),
        (__attribute__((address_space(3))) void*)lB1, 16, 0, 0);
    __syncthreads();

    short8 af[4], bv[4];
#pragma unroll
    for (int i = 0; i < 4; i++) af[i] = *(const short8*)(As + a_base + i * 16 * BK);
#pragma unroll
    for (int j = 0; j < 4; j++) bv[j] = *(const short8*)(Bs + b_base + j * 16 * BK);
#pragma unroll
    for (int i = 0; i < 4; i++)
#pragma unroll
      for (int j = 0; j < 4; j++)
        acc[i][j] = __builtin_amdgcn_mfma_f32_16x16x32_bf16(af[i], bv[j], acc[i][j], 0, 0, 0);
  }

  // epilogue: C/D layout col=lane&15 (n), row=(lane>>4)*4+reg (m)
#pragma unroll
  for (int i = 0; i < 4; i++) {
    int row0 = bm + wr * 64 + i * 16 + q * 4;
#pragma unroll
    for (int j = 0; j < 4; j++) {
      int col = bn + wc * 64 + j * 16 + cl;
      int gate = col >> 11;   // uniform per 16-wide tile (boundaries at 2048)
      const float* bp = (gate == 0) ? b0 : (gate == 1) ? b1 : (gate == 2) ? b2 : b3;
      float bvl = bp[col & 2047];
#pragma unroll
      for (int r = 0; r < 4; r++)
        C[(size_t)(row0 + r) * N + col] = f2bf(acc[i][j][r] + bvl);
    }
  }
}

__device__ __forceinline__ float2 block_sum2(float a, float b, float* scr, int t) {
#pragma unroll
  for (int o = 32; o; o >>= 1) { a += __shfl_xor(a, o); b += __shfl_xor(b, o); }
  __syncthreads();                       // protect scr from previous use
  if ((t & 63) == 0) { scr[(t >> 6) * 2] = a; scr[(t >> 6) * 2 + 1] = b; }
  __syncthreads();
  return make_float2(scr[0] + scr[2] + scr[4] + scr[6],
                     scr[1] + scr[3] + scr[5] + scr[7]);
}

// LN over concat(xp[b], h[b]) width 4096, then tanh, store bf16 combined row.
__global__ __launch_bounds__(256)
void ln_tanh_combined(const unsigned short* __restrict__ xp,
                      const float* __restrict__ h,
                      const float* __restrict__ g_ln, const float* __restrict__ b_ln,
                      unsigned short* __restrict__ comb) {
  __shared__ float red[8];
  const int b = blockIdx.x, t = threadIdx.x;
  float xv[8], hv[8];
  unpack8(((const uint4*)(xp + (size_t)b * 2048))[t], xv);
  const float4* hr = (const float4*)(h + (size_t)b * 2048);
  float4 h0 = hr[2*t], h1 = hr[2*t+1];
  hv[0]=h0.x; hv[1]=h0.y; hv[2]=h0.z; hv[3]=h0.w;
  hv[4]=h1.x; hv[5]=h1.y; hv[6]=h1.z; hv[7]=h1.w;
  float s = 0.f, ss = 0.f;
#pragma unroll
  for (int e = 0; e < 8; e++) {
    s += xv[e] + hv[e];
    ss += xv[e]*xv[e] + hv[e]*hv[e];
  }
  float2 r = block_sum2(s, ss, red, t);
  float mean = r.x * (1.f/4096.f);
  float var  = r.y * (1.f/4096.f) - mean*mean;
  float rs = rsqrtf(var + 1e-5f);
  float o0[8], o1[8];
  const int j0 = t * 8;
#pragma unroll
  for (int e = 0; e < 8; e++) {
    int j = j0 + e;
    o0[e] = tanh_fast((xv[e] - mean) * rs * g_ln[j] + b_ln[j]);
  }
#pragma unroll
  for (int e = 0; e < 8; e++) {
    int j = 2048 + j0 + e;
    o1[e] = tanh_fast((hv[e] - mean) * rs * g_ln[j] + b_ln[j]);
  }
  uint4* cr = (uint4*)(comb + (size_t)b * 4096);
  cr[t] = pack8(o0);
  cr[256 + t] = pack8(o1);
}

// Per batch row: 4 gate LNs + activations, cell LN, hidden LN, write f32 out.
__global__ __launch_bounds__(256)
void finalize(const unsigned short* __restrict__ gates, const float* __restrict__ c,
              const float* __restrict__ g_f,  const float* __restrict__ bt_f,
              const float* __restrict__ g_i,  const float* __restrict__ bt_i,
              const float* __restrict__ g_c2, const float* __restrict__ bt_c2,
              const float* __restrict__ g_o,  const float* __restrict__ bt_o,
              const float* __restrict__ g_cn, const float* __restrict__ b_cn,
              const float* __restrict__ g_hn, const float* __restrict__ b_hn,
              float* __restrict__ out) {
  __shared__ float red32[32];
  const int b = blockIdx.x, t = threadIdx.x;
  const unsigned short* gr = gates + (size_t)b * 8192;
  float fv[8], iv[8], c2v[8], ov[8];
  unpack8(((const uint4*)(gr        ))[t], fv);
  unpack8(((const uint4*)(gr + 2048))[t], iv);
  unpack8(((const uint4*)(gr + 4096))[t], c2v);
  unpack8(((const uint4*)(gr + 6144))[t], ov);

  // combined stats reduction for all 4 gates: s[f,i,c2,o] + ss[...]
  float s[8] = {0,0,0,0,0,0,0,0};
#pragma unroll
  for (int e = 0; e < 8; e++) {
    s[0] += fv[e];  s[1] += fv[e]*fv[e];
    s[2] += iv[e];  s[3] += iv[e]*iv[e];
    s[4] += c2v[e]; s[5] += c2v[e]*c2v[e];
    s[6] += ov[e];  s[7] += ov[e]*ov[e];
  }
#pragma unroll
  for (int o = 32; o; o >>= 1)
#pragma unroll
    for (int q2 = 0; q2 < 8; q2++) s[q2] += __shfl_xor(s[q2], o);
  if ((t & 63) == 0) {
#pragma unroll
    for (int q2 = 0; q2 < 8; q2++) red32[(t >> 6) * 8 + q2] = s[q2];
  }
  __syncthreads();
#pragma unroll
  for (int q2 = 0; q2 < 8; q2++)
    s[q2] = red32[q2] + red32[8 + q2] + red32[16 + q2] + red32[24 + q2];

  const float inv = 1.f / 2048.f;
  float m_f = s[0]*inv, rs_f = rsqrtf(s[1]*inv - m_f*m_f + 1e-5f);
  float m_i = s[2]*inv, rs_i = rsqrtf(s[3]*inv - m_i*m_i + 1e-5f);
  float m_c = s[4]*inv, rs_c = rsqrtf(s[5]*inv - m_c*m_c + 1e-5f);
  float m_o = s[6]*inv, rs_o = rsqrtf(s[7]*inv - m_o*m_o + 1e-5f);

  const int j0 = t * 8;
  float cv[8];
  const float4* crp = (const float4*)(c + (size_t)b * 2048);
  float4 c0 = crp[2*t], c1 = crp[2*t+1];
  cv[0]=c0.x; cv[1]=c0.y; cv[2]=c0.z; cv[3]=c0.w;
  cv[4]=c1.x; cv[5]=c1.y; cv[6]=c1.z; cv[7]=c1.w;

  float cellraw[8], os[8];
  float s2 = 0.f, ss2 = 0.f;
#pragma unroll
  for (int e = 0; e < 8; e++) {
    int j = j0 + e;
    float fgate = sigmoid_fast((fv[e]  - m_f) * rs_f * g_f[j]  + bt_f[j]);
    float igate = sigmoid_fast((iv[e]  - m_i) * rs_i * g_i[j]  + bt_i[j]);
    float cgate = tanh_fast   ((c2v[e] - m_c) * rs_c * g_c2[j] + bt_c2[j]);
    os[e]       = sigmoid_fast((ov[e]  - m_o) * rs_o * g_o[j]  + bt_o[j]);
    cellraw[e] = fgate * cv[e] + igate * cgate;
    s2 += cellraw[e]; ss2 += cellraw[e]*cellraw[e];
  }
  float2 rc = block_sum2(s2, ss2, red32, t);
  float m2 = rc.x * inv, rs2 = rsqrtf(rc.y * inv - m2*m2 + 1e-5f);

  float nc[8], hraw[8];
  float s3 = 0.f, ss3 = 0.f;
#pragma unroll
  for (int e = 0; e < 8; e++) {
    int j = j0 + e;
    nc[e] = (cellraw[e] - m2) * rs2 * g_cn[j] + b_cn[j];
    hraw[e] = os[e] * tanh_fast(nc[e]);
    s3 += hraw[e]; ss3 += hraw[e]*hraw[e];
  }
  float2 rh = block_sum2(s3, ss3, red32, t);
  float m3 = rh.x * inv, rs3 = rsqrtf(rh.y * inv - m3*m3 + 1e-5f);

  float nh[8];
#pragma unroll
  for (int e = 0; e < 8; e++) {
    int j = j0 + e;
    nh[e] = tanh_fast((hraw[e] - m3) * rs3 * g_hn[j] + b_hn[j]);
  }
  // out: [0][b][:] = next_hidden, [1][b][:] = next_cell ; B*H = 16777216
  float4* oh = (float4*)(out + (size_t)b * 2048 + j0);
  oh[0] = make_float4(nh[0], nh[1], nh[2], nh[3]);
  oh[1] = make_float4(nh[4], nh[5], nh[6], nh[7]);
  float4* oc = (float4*)(out + 16777216ull + (size_t)b * 2048 + j0);
  oc[0] = make_float4(nc[0], nc[1], nc[2], nc[3]);
  oc[1] = make_float4(nc[4], nc[5], nc[6], nc[7]);
}

extern "C" void kernel_launch(void* const* d_in, const int* in_sizes, int n_in,
                              void* d_out, int out_size, void* d_ws, size_t ws_size,
                              hipStream_t stream) {
  const float* x      = (const float*)d_in[0];
  const float* h      = (const float*)d_in[1];
  const float* c      = (const float*)d_in[2];
  const float* W_proj = (const float*)d_in[3];
  const float* b_proj = (const float*)d_in[4];
  const float* g_ln   = (const float*)d_in[5];
  const float* b_ln   = (const float*)d_in[6];
  const float* g_cn   = (const float*)d_in[7];
  const float* b_cn   = (const float*)d_in[8];
  const float* g_hn   = (const float*)d_in[9];
  const float* b_hn   = (const float*)d_in[10];
  const float* W_f    = (const float*)d_in[11];
  const float* b_f    = (const float*)d_in[12];
  const float* g_f    = (const float*)d_in[13];
  const float* bt_f   = (const float*)d_in[14];
  const float* W_i    = (const float*)d_in[15];
  const float* b_i    = (const float*)d_in[16];
  const float* g_i    = (const float*)d_in[17];
  const float* bt_i   = (const float*)d_in[18];
  const float* W_c2   = (const float*)d_in[19];
  const float* b_c2   = (const float*)d_in[20];
  const float* g_c2   = (const float*)d_in[21];
  const float* bt_c2  = (const float*)d_in[22];
  const float* W_o    = (const float*)d_in[23];
  const float* b_o    = (const float*)d_in[24];
  const float* g_o    = (const float*)d_in[25];
  const float* bt_o   = (const float*)d_in[26];
  float* out = (float*)d_out;
  char* ws = (char*)d_ws;

  // ws layout (256 MB total):
  //   [0,   64M): Wcat bf16 [8192][4096]  (W_f;W_i;W_c2;W_o)
  //   [64M, 128M): combined bf16 [8192][4096]
  //   [128M,256M): gates bf16 [8192][8192]   (phase 2)
  //     overlaid phase 1: x_bf16 (8M) | wp_bf16 (2M) | xp_bf16 (32M)
  unsigned short* Wcat  = (unsigned short*)(ws);
  unsigned short* comb  = (unsigned short*)(ws + 67108864ull);
  unsigned short* gates = (unsigned short*)(ws + 134217728ull);
  unsigned short* xbf   = (unsigned short*)(ws + 134217728ull);
  unsigned short* wpbf  = (unsigned short*)(ws + 142606336ull);
  unsigned short* xpbf  = (unsigned short*)(ws + 144703488ull);

  // 1) one merged convert launch (x, W_proj, 4 gate weights)
  cvt_all<<<18944, 256, 0, stream>>>(x, W_proj, W_f, W_i, W_c2, W_o,
                                     xbf, wpbf, Wcat);

  // 2) xp = x @ Wp^T + bp   (M=8192, N=2048, K=512) -> bf16
  dim3 g1(2048 / BN, 8192 / BM);
  gemm_bt_bf16<<<g1, 256, 0, stream>>>(xbf, wpbf, b_proj, b_proj, b_proj, b_proj,
                                       xpbf, 8192, 2048, 512);

  // 3) combined = tanh(LN(concat(xp,h)))
  ln_tanh_combined<<<8192, 256, 0, stream>>>(xpbf, h, g_ln, b_ln, comb);

  // 4) gates = comb @ Wcat^T + bias   (M=8192, N=8192, K=4096) -> bf16
  dim3 g2(8192 / BN, 8192 / BM);
  gemm_bt_bf16<<<g2, 256, 0, stream>>>(comb, Wcat, b_f, b_i, b_c2, b_o,
                                       gates, 8192, 8192, 4096);

  // 5) gate LNs + activations + cell/hidden LNs -> out
  finalize<<<8192, 256, 0, stream>>>(gates, c, g_f, bt_f, g_i, bt_i, g_c2, bt_c2,
                                     g_o, bt_o, g_cn, b_cn, g_hn, b_hn, out);
}